// Round 5
// baseline (214.325 us; speedup 1.0000x reference)
//
#include <hip/hip_runtime.h>
#include <hip/hip_bf16.h>
#include <stdint.h>

// Problem constants
#define B_  2
#define S_  2048
#define D_  1024
#define H_  16
#define DQ_ 64
#define QT_ (S_/64)   // 32 q-tiles (64-row) per (b,h)
// exp(x*0.125 - 16) = exp2(x*0.18033688 - 23.083121)
#define EXPC1_ 0.18033688f
#define EXPC2_ (-23.083121f)

typedef float f32x4 __attribute__((ext_vector_type(4)));
typedef short bf16x8 __attribute__((ext_vector_type(8)));

__device__ __forceinline__ unsigned short f2bf(float f) {
    uint32_t u = __float_as_uint(f);
    u += 0x7fffu + ((u >> 16) & 1u);   // round-to-nearest-even
    return (unsigned short)(u >> 16);
}
__device__ __forceinline__ float bf2f(unsigned short u) {
    return __uint_as_float(((uint32_t)u) << 16);
}
__device__ __forceinline__ bf16x8 packbf8(float4 a, float4 b) {
    bf16x8 r;
    r[0]=(short)f2bf(a.x); r[1]=(short)f2bf(a.y);
    r[2]=(short)f2bf(a.z); r[3]=(short)f2bf(a.w);
    r[4]=(short)f2bf(b.x); r[5]=(short)f2bf(b.y);
    r[6]=(short)f2bf(b.z); r[7]=(short)f2bf(b.w);
    return r;
}

// ---------------------------------------------------------------------------
// Kernel 1: prep — K fp32->bf16, Wo fp32->bf16, V transpose->bf16 (+Pv
// column partials for the row-0 mean(V) path). 6144 blocks:
//   [0,1024): V transpose   [1024,5120): K convert   [5120,6144): Wo convert
// ---------------------------------------------------------------------------
__global__ __launch_bounds__(256) void prep_kernel(
    const float* __restrict__ K, const float* __restrict__ V,
    const float* __restrict__ W,
    unsigned short* __restrict__ Kb, unsigned short* __restrict__ Vt,
    unsigned short* __restrict__ Wb, float* __restrict__ Pv)
{
    __shared__ unsigned short Ls[64][72];
    const int blk = blockIdx.x, tid = threadIdx.x;

    if (blk < 1024) {
        const int st = blk & 31, h = (blk >> 5) & 15, b = blk >> 9;
        {
            int row = tid >> 2, col0 = (tid & 3) * 16;   // row=s-in-tile, col=dq
            const float* src = V + (((size_t)b*S_ + (size_t)st*64 + row)*D_ + h*64 + col0);
            float4 f0 = ((const float4*)src)[0];
            float4 f1 = ((const float4*)src)[1];
            float4 f2 = ((const float4*)src)[2];
            float4 f3 = ((const float4*)src)[3];
            unsigned short* d = &Ls[row][col0];
            d[0]=f2bf(f0.x); d[1]=f2bf(f0.y); d[2]=f2bf(f0.z); d[3]=f2bf(f0.w);
            d[4]=f2bf(f1.x); d[5]=f2bf(f1.y); d[6]=f2bf(f1.z); d[7]=f2bf(f1.w);
            d[8]=f2bf(f2.x); d[9]=f2bf(f2.y); d[10]=f2bf(f2.z); d[11]=f2bf(f2.w);
            d[12]=f2bf(f3.x); d[13]=f2bf(f3.y); d[14]=f2bf(f3.z); d[15]=f2bf(f3.w);
        }
        __syncthreads();
        {
            int d = tid >> 2, scol = (tid & 3) * 16;     // d = dq row of Vt
            unsigned short tmp[16];
            float psum = 0.f;
            #pragma unroll
            for (int i = 0; i < 16; ++i) {
                unsigned short u = Ls[scol + i][d];
                tmp[i] = u;
                psum += bf2f(u);
            }
            unsigned short* dst = Vt + ((size_t)((b*H_ + h)*64 + d)*S_ + st*64 + scol);
            ((uint4*)dst)[0] = *((uint4*)tmp);
            ((uint4*)dst)[1] = *((uint4*)(tmp + 8));
            psum += __shfl_xor(psum, 1);
            psum += __shfl_xor(psum, 2);
            if ((tid & 3) == 0)
                Pv[((size_t)(b*H_ + h)*64 + d)*32 + st] = psum;
        }
    } else if (blk < 5120) {
        int i = (blk - 1024)*256 + tid;     // < B*S*D/4
        float4 f = ((const float4*)K)[i];
        ushort4 o;
        o.x = f2bf(f.x); o.y = f2bf(f.y); o.z = f2bf(f.z); o.w = f2bf(f.w);
        ((ushort4*)Kb)[i] = o;
    } else {
        int i = (blk - 5120)*256 + tid;     // < D*D/4
        float4 f = ((const float4*)W)[i];
        ushort4 o;
        o.x = f2bf(f.x); o.y = f2bf(f.y); o.z = f2bf(f.z); o.w = f2bf(f.w);
        ((ushort4*)Wb)[i] = o;
    }
}

// ---------------------------------------------------------------------------
// Kernel 2: flash attention. 128-thr blocks = 2 waves x 32 q-rows.
// S computed TRANSPOSED (S^T = K Q^T): A = K-frag from LDS, B = Q-frag regs.
// P lands with 4 consecutive keys per lane -> b64 Ps writes, b128 reads.
// Fixed-max softmax (exp2), dbuf K/V LDS, 1 barrier/K-tile, q-tile pairing
// {pa, 31-pa} = 33 iters/block. Grid 512: bid = g + 32*pa (XCD locality).
// Row q=0 (fully masked -> mean(V)) from Pv partials by pa==0 blocks.
// ---------------------------------------------------------------------------
__global__ __launch_bounds__(128, 2) void attn_kernel(
    const float* __restrict__ Q,
    const unsigned short* __restrict__ Kb,
    const unsigned short* __restrict__ Vtb,
    const float* __restrict__ Pv,
    unsigned short* __restrict__ ctx,
    const int* __restrict__ maskp)
{
    __shared__ unsigned short Ks [2][64][72];   // [buf][key][dq]
    __shared__ unsigned short Vts[2][64][72];   // [buf][dq][key]
    __shared__ unsigned short Ps [2][32][72];   // per-wave P: [q][key]

    const int bid = blockIdx.x;
    const int g = bid & 31, pa = bid >> 5;      // g = h + 16*b
    const int h = g & 15, b = g >> 4;
    const int tid  = threadIdx.x;
    const int wave = tid >> 6, lane = tid & 63;
    const int quad = lane >> 4, ln = lane & 15;
    const int maskv = maskp[0];

    // fused mean(V) -> ctx row 0, cols [h*64, h*64+64)
    if (maskv && pa == 0 && tid < 64) {
        const float* p = Pv + ((size_t)(b*H_ + h)*64 + tid)*32;
        float s = 0.f;
        #pragma unroll
        for (int i = 0; i < 32; ++i) s += p[i];
        ctx[(size_t)b*S_*D_ + h*64 + tid] = f2bf(s * (1.0f/S_));
    }

    // staging: 128 threads cover 64 rows x 64 cols (each thread 64B/tensor)
    const int srow = tid >> 1, scol = (tid & 1)*32;
    const unsigned short* kbase =
        Kb + (((size_t)b*S_ + srow)*D_ + h*64 + scol);          // + j*64*D_
    const unsigned short* vbase =
        Vtb + ((size_t)((b*H_ + h)*64 + srow)*S_ + scol);       // + j*64

    const int qloc = wave*32 + ln;   // + qt2*16 = q within 64-row block

    for (int t = 0; t < 2; ++t) {
        const int qt = t ? (QT_-1 - pa) : pa;
        const int niter = maskv ? (qt + 1) : QT_;

        // Q B-fragments: fp32 global -> bf16 regs. bq[qt2][dqs]:
        // lane holds Q[q = qt*64 + wave*32 + qt2*16 + ln][dq = dqs*32 + quad*8 + j]
        bf16x8 bq[2][2];
        #pragma unroll
        for (int qt2 = 0; qt2 < 2; ++qt2) {
            const float* qr = Q + (((size_t)b*S_ + (size_t)qt*64 + wave*32 + qt2*16 + ln)*D_
                                   + h*64 + quad*8);
            #pragma unroll
            for (int dqs = 0; dqs < 2; ++dqs) {
                float4 f0 = ((const float4*)(qr + dqs*32))[0];
                float4 f1 = ((const float4*)(qr + dqs*32))[1];
                bq[qt2][dqs] = packbf8(f0, f1);
            }
        }

        // prefetch tile 0 (4 uint4 per tensor per thread)
        uint4 kr[4], vr[4];
        #pragma unroll
        for (int u = 0; u < 4; ++u) {
            kr[u] = ((const uint4*)kbase)[u];
            vr[u] = ((const uint4*)vbase)[u];
        }

        f32x4 o[2][4] = {};               // [qt2][dd] PV accum (C-layout)
        float l4[2] = {0.f, 0.f};         // per-lane l partial (q = col)
        const int qg0 = qt*64 + wave*32;  // + qt2*16 + ln = global q

        for (int j = 0; j < niter; ++j) {
            const int cur = j & 1;
            #pragma unroll
            for (int u = 0; u < 4; ++u) {
                *((uint4*)&Ks [cur][srow][scol + u*8]) = kr[u];
                *((uint4*)&Vts[cur][srow][scol + u*8]) = vr[u];
            }
            if (j + 1 < niter) {
                const unsigned short* kp = kbase + (size_t)(j+1)*64*D_;
                const unsigned short* vp = vbase + (j+1)*64;
                #pragma unroll
                for (int u = 0; u < 4; ++u) {
                    kr[u] = ((const uint4*)kp)[u];
                    vr[u] = ((const uint4*)vp)[u];
                }
            }
            __syncthreads();

            // ---- S^T = K Q^T : s[kt][qt2], D[m=key][n=q] ----
            f32x4 s[4][2] = {};
            #pragma unroll
            for (int dqs = 0; dqs < 2; ++dqs)
                #pragma unroll
                for (int kt = 0; kt < 4; ++kt) {
                    bf16x8 aK = *(const bf16x8*)&Ks[cur][kt*16 + ln][dqs*32 + quad*8];
                    #pragma unroll
                    for (int qt2 = 0; qt2 < 2; ++qt2)
                        s[kt][qt2] = __builtin_amdgcn_mfma_f32_16x16x32_bf16(
                            aK, bq[qt2][dqs], s[kt][qt2], 0,0,0);
                }

            // ---- P = exp(S*0.125 - 16); l partial; Ps b64 writes ----
            const int diag = maskv && (j == qt);
            #pragma unroll
            for (int qt2 = 0; qt2 < 2; ++qt2) {
                const int ql = qloc + qt2*16;   // q within 64 (for diag mask)
                #pragma unroll
                for (int kt = 0; kt < 4; ++kt) {
                    float e[4];
                    #pragma unroll
                    for (int r = 0; r < 4; ++r) {
                        float v = exp2f(fmaf(s[kt][qt2][r], EXPC1_, EXPC2_));
                        if (diag && (kt*16 + quad*4 + r) >= ql) v = 0.f;
                        e[r] = v;
                    }
                    l4[qt2] += (e[0] + e[1]) + (e[2] + e[3]);
                    uint2 w;
                    w.x = ((uint32_t)f2bf(e[1]) << 16) | f2bf(e[0]);
                    w.y = ((uint32_t)f2bf(e[3]) << 16) | f2bf(e[2]);
                    *((uint2*)&Ps[wave][qt2*16 + ln][kt*16 + quad*4]) = w;
                }
            }
            // no barrier: Ps is per-wave; DS pipe in-order per wave

            // ---- O += P V : A = Ps (m=q), B = Vts (n=dq) ----
            bf16x8 ap[2][2];
            #pragma unroll
            for (int qt2 = 0; qt2 < 2; ++qt2)
                #pragma unroll
                for (int ks2 = 0; ks2 < 2; ++ks2)
                    ap[qt2][ks2] = *(const bf16x8*)&Ps[wave][qt2*16 + ln][ks2*32 + quad*8];
            #pragma unroll
            for (int ks2 = 0; ks2 < 2; ++ks2)
                #pragma unroll
                for (int dd = 0; dd < 4; ++dd) {
                    bf16x8 bv = *(const bf16x8*)&Vts[cur][dd*16 + ln][ks2*32 + quad*8];
                    #pragma unroll
                    for (int qt2 = 0; qt2 < 2; ++qt2)
                        o[qt2][dd] = __builtin_amdgcn_mfma_f32_16x16x32_bf16(
                            ap[qt2][ks2], bv, o[qt2][dd], 0,0,0);
                }
        }

        // ---- epilogue ----
        // l total per q: lanes sharing q are {l, l^16, l^32, l^48}
        #pragma unroll
        for (int qt2 = 0; qt2 < 2; ++qt2) {
            l4[qt2] += __shfl_xor(l4[qt2], 16);
            l4[qt2] += __shfl_xor(l4[qt2], 32);
        }
        // O C-layout: lane holds col dd*16+ln, rows q = qt2*16 + quad*4 + r
        float inv[2][4];
        #pragma unroll
        for (int qt2 = 0; qt2 < 2; ++qt2)
            #pragma unroll
            for (int r = 0; r < 4; ++r)
                inv[qt2][r] = 1.0f / __shfl(l4[qt2], quad*4 + r);
        #pragma unroll
        for (int qt2 = 0; qt2 < 2; ++qt2)
            #pragma unroll
            for (int dd = 0; dd < 4; ++dd)
                #pragma unroll
                for (int r = 0; r < 4; ++r) {
                    int q = qg0 + qt2*16 + quad*4 + r;
                    if (maskv && q == 0) continue;   // row 0 = mean(V)
                    int c = h*64 + dd*16 + ln;
                    ctx[((size_t)b*S_ + q)*D_ + c] = f2bf(o[qt2][dd][r]*inv[qt2][r]);
                }
        __syncthreads();   // before next pass re-stages buffers
    }
}

// ---------------------------------------------------------------------------
// Kernel 3: out = ctx @ Wo^T + bias   (M=4096, N=1024, K=1024, bf16 MFMA)
// 64x128 tile, 4 waves (each 64x32), BK=64, double-buffered, 1 barrier/kt.
// Grid (8, 64) = 512 blocks; bid%8 = nt0 -> per-XCD Wo panel locality.
// ---------------------------------------------------------------------------
__global__ __launch_bounds__(256, 2) void proj_kernel(
    const unsigned short* __restrict__ A,    // ctx bf16 [4096][1024]
    const unsigned short* __restrict__ Bw,   // Wo bf16  [1024][1024]
    const float* __restrict__ bias,
    float* __restrict__ out)
{
    __shared__ unsigned short As[2][64][72];
    __shared__ unsigned short Bs[2][128][72];
    const int nt0 = blockIdx.x;   // 0..7   (N panel)
    const int mt0 = blockIdx.y;   // 0..63  (M panel)
    const int tid  = threadIdx.x;
    const int wave = tid >> 6, lane = tid & 63;
    const int quad = lane >> 4, ln = lane & 15;

    const int arow = tid >> 2, acol = (tid & 3)*16;   // A: 64 rows x 64 cols
    const int brow = tid >> 1, bcol = (tid & 1)*32;   // B: 128 rows x 64 cols
    const unsigned short* aptr = A  + ((size_t)(mt0*64  + arow)*1024 + acol);
    const unsigned short* bptr = Bw + ((size_t)(nt0*128 + brow)*1024 + bcol);

    uint4 a0 = ((const uint4*)aptr)[0], a1 = ((const uint4*)aptr)[1];
    uint4 b0 = ((const uint4*)bptr)[0], b1 = ((const uint4*)bptr)[1],
          b2 = ((const uint4*)bptr)[2], b3 = ((const uint4*)bptr)[3];

    f32x4 acc[4][2] = {};

    for (int kt = 0; kt < 16; ++kt) {
        const int cur = kt & 1;
        *((uint4*)&As[cur][arow][acol])    = a0;
        *((uint4*)&As[cur][arow][acol+8])  = a1;
        *((uint4*)&Bs[cur][brow][bcol])    = b0;
        *((uint4*)&Bs[cur][brow][bcol+8])  = b1;
        *((uint4*)&Bs[cur][brow][bcol+16]) = b2;
        *((uint4*)&Bs[cur][brow][bcol+24]) = b3;
        uint4 na0, na1, nb0, nb1, nb2, nb3;
        if (kt < 15) {
            const unsigned short* ap = aptr + (kt+1)*64;
            const unsigned short* bp = bptr + (kt+1)*64;
            na0 = ((const uint4*)ap)[0]; na1 = ((const uint4*)ap)[1];
            nb0 = ((const uint4*)bp)[0]; nb1 = ((const uint4*)bp)[1];
            nb2 = ((const uint4*)bp)[2]; nb3 = ((const uint4*)bp)[3];
        }
        __syncthreads();
        #pragma unroll
        for (int ks = 0; ks < 2; ++ks) {
            bf16x8 am[4], bn[2];
            #pragma unroll
            for (int i = 0; i < 4; ++i)
                am[i] = *(const bf16x8*)&As[cur][i*16 + ln][ks*32 + quad*8];
            #pragma unroll
            for (int i = 0; i < 2; ++i)
                bn[i] = *(const bf16x8*)&Bs[cur][wave*32 + i*16 + ln][ks*32 + quad*8];
            #pragma unroll
            for (int mi = 0; mi < 4; ++mi)
                #pragma unroll
                for (int ni = 0; ni < 2; ++ni)
                    acc[mi][ni] = __builtin_amdgcn_mfma_f32_16x16x32_bf16(
                        am[mi], bn[ni], acc[mi][ni], 0,0,0);
        }
        a0 = na0; a1 = na1;
        b0 = nb0; b1 = nb1; b2 = nb2; b3 = nb3;
    }

    #pragma unroll
    for (int mi = 0; mi < 4; ++mi)
        #pragma unroll
        for (int ni = 0; ni < 2; ++ni) {
            int row = mt0*64 + mi*16 + quad*4;
            int col = nt0*128 + wave*32 + ni*16 + ln;
            float bv = bias[col];
            #pragma unroll
            for (int r = 0; r < 4; ++r)
                out[(size_t)(row + r)*1024 + col] = acc[mi][ni][r] + bv;
        }
}

// ---------------------------------------------------------------------------
extern "C" void kernel_launch(void* const* d_in, const int* in_sizes, int n_in,
                              void* d_out, int out_size, void* d_ws, size_t ws_size,
                              hipStream_t stream)
{
    const float* Q   = (const float*)d_in[0];
    const float* K   = (const float*)d_in[1];
    const float* V   = (const float*)d_in[2];
    const float* Wo  = (const float*)d_in[3];
    const float* Wb  = (const float*)d_in[4];
    const int* maskp = (const int*)d_in[5];
    float* out = (float*)d_out;

    // workspace layout (ushort units)
    unsigned short* Kb   = (unsigned short*)d_ws;
    unsigned short* Vtb  = Kb  + (size_t)B_*S_*D_;
    unsigned short* Wob  = Vtb + (size_t)B_*S_*D_;
    unsigned short* ctxb = Wob + (size_t)D_*D_;
    float* Pv = (float*)(ctxb + (size_t)B_*S_*D_);   // [B*H*64][32] partials

    prep_kernel<<<6144, 256, 0, stream>>>(K, V, Wo, Kb, Vtb, Wob, Pv);
    attn_kernel<<<512, 128, 0, stream>>>(Q, Kb, Vtb, Pv, ctxb, maskp);
    proj_kernel<<<dim3(8, 64), 256, 0, stream>>>(ctxb, Wob, Wb, out);
}

// Round 6
// 175.910 us; speedup vs baseline: 1.2184x; 1.2184x over previous
//
#include <hip/hip_runtime.h>
#include <hip/hip_bf16.h>
#include <stdint.h>

// Problem constants
#define B_  2
#define S_  2048
#define D_  1024
#define H_  16
#define DQ_ 64
#define QT_ (S_/64)   // 32 q-tiles (64-row) per (b,h)
// exp(x*0.125 - 16) = exp2(x*0.18033688 - 23.083121)
#define EXPC1_ 0.18033688f
#define EXPC2_ (-23.083121f)

typedef float f32x4 __attribute__((ext_vector_type(4)));
typedef short bf16x8 __attribute__((ext_vector_type(8)));

__device__ __forceinline__ unsigned short f2bf(float f) {
    uint32_t u = __float_as_uint(f);
    u += 0x7fffu + ((u >> 16) & 1u);   // round-to-nearest-even
    return (unsigned short)(u >> 16);
}
__device__ __forceinline__ float bf2f(unsigned short u) {
    return __uint_as_float(((uint32_t)u) << 16);
}
__device__ __forceinline__ bf16x8 packbf8(float4 a, float4 b) {
    bf16x8 r;
    r[0]=(short)f2bf(a.x); r[1]=(short)f2bf(a.y);
    r[2]=(short)f2bf(a.z); r[3]=(short)f2bf(a.w);
    r[4]=(short)f2bf(b.x); r[5]=(short)f2bf(b.y);
    r[6]=(short)f2bf(b.z); r[7]=(short)f2bf(b.w);
    return r;
}

// ---------------------------------------------------------------------------
// Kernel 1: prep — K fp32->bf16, Wo fp32->bf16, V transpose->bf16 (+Pv
// column partials for the row-0 mean(V) path). 6144 blocks:
//   [0,1024): V transpose   [1024,5120): K convert   [5120,6144): Wo convert
// ---------------------------------------------------------------------------
__global__ __launch_bounds__(256) void prep_kernel(
    const float* __restrict__ K, const float* __restrict__ V,
    const float* __restrict__ W,
    unsigned short* __restrict__ Kb, unsigned short* __restrict__ Vt,
    unsigned short* __restrict__ Wb, float* __restrict__ Pv)
{
    __shared__ unsigned short Ls[64][72];
    const int blk = blockIdx.x, tid = threadIdx.x;

    if (blk < 1024) {
        const int st = blk & 31, h = (blk >> 5) & 15, b = blk >> 9;
        {
            int row = tid >> 2, col0 = (tid & 3) * 16;   // row=s-in-tile, col=dq
            const float* src = V + (((size_t)b*S_ + (size_t)st*64 + row)*D_ + h*64 + col0);
            float4 f0 = ((const float4*)src)[0];
            float4 f1 = ((const float4*)src)[1];
            float4 f2 = ((const float4*)src)[2];
            float4 f3 = ((const float4*)src)[3];
            unsigned short* d = &Ls[row][col0];
            d[0]=f2bf(f0.x); d[1]=f2bf(f0.y); d[2]=f2bf(f0.z); d[3]=f2bf(f0.w);
            d[4]=f2bf(f1.x); d[5]=f2bf(f1.y); d[6]=f2bf(f1.z); d[7]=f2bf(f1.w);
            d[8]=f2bf(f2.x); d[9]=f2bf(f2.y); d[10]=f2bf(f2.z); d[11]=f2bf(f2.w);
            d[12]=f2bf(f3.x); d[13]=f2bf(f3.y); d[14]=f2bf(f3.z); d[15]=f2bf(f3.w);
        }
        __syncthreads();
        {
            int d = tid >> 2, scol = (tid & 3) * 16;     // d = dq row of Vt
            unsigned short tmp[16];
            float psum = 0.f;
            #pragma unroll
            for (int i = 0; i < 16; ++i) {
                unsigned short u = Ls[scol + i][d];
                tmp[i] = u;
                psum += bf2f(u);
            }
            unsigned short* dst = Vt + ((size_t)((b*H_ + h)*64 + d)*S_ + st*64 + scol);
            ((uint4*)dst)[0] = *((uint4*)tmp);
            ((uint4*)dst)[1] = *((uint4*)(tmp + 8));
            psum += __shfl_xor(psum, 1);
            psum += __shfl_xor(psum, 2);
            if ((tid & 3) == 0)
                Pv[((size_t)(b*H_ + h)*64 + d)*32 + st] = psum;
        }
    } else if (blk < 5120) {
        int i = (blk - 1024)*256 + tid;     // < B*S*D/4
        float4 f = ((const float4*)K)[i];
        ushort4 o;
        o.x = f2bf(f.x); o.y = f2bf(f.y); o.z = f2bf(f.z); o.w = f2bf(f.w);
        ((ushort4*)Kb)[i] = o;
    } else {
        int i = (blk - 5120)*256 + tid;     // < D*D/4
        float4 f = ((const float4*)W)[i];
        ushort4 o;
        o.x = f2bf(f.x); o.y = f2bf(f.y); o.z = f2bf(f.z); o.w = f2bf(f.w);
        ((ushort4*)Wb)[i] = o;
    }
}

// ---------------------------------------------------------------------------
// Kernel 2: flash attention. 256-thr blocks = 4 waves x 32 q-rows = 128
// q-rows per block. S computed TRANSPOSED (S^T = K Q^T) so P lands with 4
// consecutive keys per lane -> b64 Ps writes, b128 reads. Fixed-max softmax
// (exp2), dbuf K/V LDS, 1 barrier/K-tile. 128-row group pairing {pp, 15-pp}
// -> 34 iters for every block. Grid 256: bid = g + 32*pp (XCD locality,
// 4 MB K+V hot set per XCD = L2). Waves skip compute on fully-masked tiles.
// Row q=0 (fully masked -> mean(V)) from Pv partials by pp==0 blocks.
// ---------------------------------------------------------------------------
__global__ __launch_bounds__(256, 2) void attn_kernel(
    const float* __restrict__ Q,
    const unsigned short* __restrict__ Kb,
    const unsigned short* __restrict__ Vtb,
    const float* __restrict__ Pv,
    unsigned short* __restrict__ ctx,
    const int* __restrict__ maskp)
{
    __shared__ unsigned short Ks [2][64][72];   // [buf][key][dq]
    __shared__ unsigned short Vts[2][64][72];   // [buf][dq][key]
    __shared__ unsigned short Ps [4][32][72];   // per-wave P: [q][key]

    const int bid = blockIdx.x;
    const int g = bid & 31, pp = bid >> 5;      // g = h + 16*b, pp = pair id
    const int h = g & 15, b = g >> 4;
    const int tid  = threadIdx.x;
    const int wave = tid >> 6, lane = tid & 63;
    const int quad = lane >> 4, ln = lane & 15;
    const int maskv = maskp[0];

    // fused mean(V) -> ctx row 0, cols [h*64, h*64+64)
    if (maskv && pp == 0 && tid < 64) {
        const float* p = Pv + ((size_t)(b*H_ + h)*64 + tid)*32;
        float s = 0.f;
        #pragma unroll
        for (int i = 0; i < 32; ++i) s += p[i];
        ctx[(size_t)b*S_*D_ + h*64 + tid] = f2bf(s * (1.0f/S_));
    }

    // staging: 256 threads cover 64 rows x 64 cols (each thread 32B/tensor)
    const int srow = tid >> 2, scol = (tid & 3)*16;
    const unsigned short* kbase =
        Kb + (((size_t)b*S_ + srow)*D_ + h*64 + scol);          // + j*64*D_
    const unsigned short* vbase =
        Vtb + ((size_t)((b*H_ + h)*64 + srow)*S_ + scol);       // + j*64

    for (int t = 0; t < 2; ++t) {
        const int grp = t ? (15 - pp) : pp;          // 128-row group
        const int niter = maskv ? (2*grp + 2) : QT_;
        const int qw0 = grp*128 + wave*32;           // wave's first q-row

        // Q B-fragments: fp32 global -> bf16 regs.
        // bq[qt2][dqs]: lane holds Q[qw0 + qt2*16 + ln][dqs*32 + quad*8 + j]
        bf16x8 bq[2][2];
        #pragma unroll
        for (int qt2 = 0; qt2 < 2; ++qt2) {
            const float* qr = Q + (((size_t)b*S_ + qw0 + qt2*16 + ln)*D_
                                   + h*64 + quad*8);
            #pragma unroll
            for (int dqs = 0; dqs < 2; ++dqs) {
                float4 f0 = ((const float4*)(qr + dqs*32))[0];
                float4 f1 = ((const float4*)(qr + dqs*32))[1];
                bq[qt2][dqs] = packbf8(f0, f1);
            }
        }

        // prefetch tile 0 (2 uint4 per tensor per thread)
        uint4 k0 = ((const uint4*)kbase)[0], k1 = ((const uint4*)kbase)[1];
        uint4 v0 = ((const uint4*)vbase)[0], v1 = ((const uint4*)vbase)[1];

        f32x4 o[2][4] = {};               // [qt2][dd] PV accum (C-layout)
        float l4[2] = {0.f, 0.f};         // per-lane l partial (q = ln)

        if (t) __syncthreads();           // protect LDS from previous pass

        for (int j = 0; j < niter; ++j) {
            const int cur = j & 1;
            *((uint4*)&Ks [cur][srow][scol])   = k0;
            *((uint4*)&Ks [cur][srow][scol+8]) = k1;
            *((uint4*)&Vts[cur][srow][scol])   = v0;
            *((uint4*)&Vts[cur][srow][scol+8]) = v1;
            if (j + 1 < niter) {
                const unsigned short* kp = kbase + (size_t)(j+1)*64*D_;
                const unsigned short* vp = vbase + (j+1)*64;
                k0 = ((const uint4*)kp)[0]; k1 = ((const uint4*)kp)[1];
                v0 = ((const uint4*)vp)[0]; v1 = ((const uint4*)vp)[1];
            }
            __syncthreads();

            // fully-masked tile for this wave's 32 rows? contribute nothing.
            if (maskv && j*64 >= qw0 + 32) continue;

            // ---- S^T = K Q^T : s[kt][qt2], D[m=key][n=q] ----
            f32x4 s[4][2] = {};
            #pragma unroll
            for (int dqs = 0; dqs < 2; ++dqs)
                #pragma unroll
                for (int kt = 0; kt < 4; ++kt) {
                    bf16x8 aK = *(const bf16x8*)&Ks[cur][kt*16 + ln][dqs*32 + quad*8];
                    #pragma unroll
                    for (int qt2 = 0; qt2 < 2; ++qt2)
                        s[kt][qt2] = __builtin_amdgcn_mfma_f32_16x16x32_bf16(
                            aK, bq[qt2][dqs], s[kt][qt2], 0,0,0);
                }

            // ---- P = exp2(S*c1 + c2); l partial; Ps b64 writes ----
            const int needmask = maskv && (j*64 + 63 >= qw0);
            #pragma unroll
            for (int qt2 = 0; qt2 < 2; ++qt2) {
                const int qgl = qw0 + qt2*16 + ln;     // global q row
                #pragma unroll
                for (int kt = 0; kt < 4; ++kt) {
                    const int kg = j*64 + kt*16 + quad*4;
                    float e[4];
                    #pragma unroll
                    for (int r = 0; r < 4; ++r) {
                        float v = exp2f(fmaf(s[kt][qt2][r], EXPC1_, EXPC2_));
                        if (needmask && (kg + r) >= qgl) v = 0.f;
                        e[r] = v;
                    }
                    l4[qt2] += (e[0] + e[1]) + (e[2] + e[3]);
                    uint2 w;
                    w.x = ((uint32_t)f2bf(e[1]) << 16) | f2bf(e[0]);
                    w.y = ((uint32_t)f2bf(e[3]) << 16) | f2bf(e[2]);
                    *((uint2*)&Ps[wave][qt2*16 + ln][kt*16 + quad*4]) = w;
                }
            }
            // no barrier: Ps is per-wave; DS pipe in-order per wave

            // ---- O += P V : A = Ps (m=q, k=key), B = Vts (n=dq, k=key) ----
            bf16x8 ap[2][2];
            #pragma unroll
            for (int qt2 = 0; qt2 < 2; ++qt2)
                #pragma unroll
                for (int ks2 = 0; ks2 < 2; ++ks2)
                    ap[qt2][ks2] = *(const bf16x8*)&Ps[wave][qt2*16 + ln][ks2*32 + quad*8];
            #pragma unroll
            for (int ks2 = 0; ks2 < 2; ++ks2)
                #pragma unroll
                for (int dd = 0; dd < 4; ++dd) {
                    bf16x8 bv = *(const bf16x8*)&Vts[cur][dd*16 + ln][ks2*32 + quad*8];
                    #pragma unroll
                    for (int qt2 = 0; qt2 < 2; ++qt2)
                        o[qt2][dd] = __builtin_amdgcn_mfma_f32_16x16x32_bf16(
                            ap[qt2][ks2], bv, o[qt2][dd], 0,0,0);
                }
        }

        // ---- epilogue ----
        // l total per q: lanes sharing q=ln are {ln, ln^16, ln^32, ln^48}
        #pragma unroll
        for (int qt2 = 0; qt2 < 2; ++qt2) {
            l4[qt2] += __shfl_xor(l4[qt2], 16);
            l4[qt2] += __shfl_xor(l4[qt2], 32);
        }
        // O C-layout: lane holds dq col dd*16+ln, q rows qt2*16 + quad*4 + r
        float inv[2][4];
        #pragma unroll
        for (int qt2 = 0; qt2 < 2; ++qt2)
            #pragma unroll
            for (int r = 0; r < 4; ++r)
                inv[qt2][r] = 1.0f / __shfl(l4[qt2], quad*4 + r);
        #pragma unroll
        for (int qt2 = 0; qt2 < 2; ++qt2)
            #pragma unroll
            for (int dd = 0; dd < 4; ++dd)
                #pragma unroll
                for (int r = 0; r < 4; ++r) {
                    int q = qw0 + qt2*16 + quad*4 + r;
                    if (maskv && q == 0) continue;   // row 0 = mean(V)
                    int c = h*64 + dd*16 + ln;
                    ctx[((size_t)b*S_ + q)*D_ + c] = f2bf(o[qt2][dd][r]*inv[qt2][r]);
                }
        __syncthreads();   // before next pass re-stages buffers
    }
}

// ---------------------------------------------------------------------------
// Kernel 3: out = ctx @ Wo^T + bias   (M=4096, N=1024, K=1024, bf16 MFMA)
// 64x128 tile, 4 waves (each 64x32), BK=64, double-buffered, 1 barrier/kt.
// Grid (8, 64) = 512 blocks; bid%8 = nt0 -> per-XCD Wo panel locality.
// ---------------------------------------------------------------------------
__global__ __launch_bounds__(256, 2) void proj_kernel(
    const unsigned short* __restrict__ A,    // ctx bf16 [4096][1024]
    const unsigned short* __restrict__ Bw,   // Wo bf16  [1024][1024]
    const float* __restrict__ bias,
    float* __restrict__ out)
{
    __shared__ unsigned short As[2][64][72];
    __shared__ unsigned short Bs[2][128][72];
    const int nt0 = blockIdx.x;   // 0..7   (N panel)
    const int mt0 = blockIdx.y;   // 0..63  (M panel)
    const int tid  = threadIdx.x;
    const int wave = tid >> 6, lane = tid & 63;
    const int quad = lane >> 4, ln = lane & 15;

    const int arow = tid >> 2, acol = (tid & 3)*16;   // A: 64 rows x 64 cols
    const int brow = tid >> 1, bcol = (tid & 1)*32;   // B: 128 rows x 64 cols
    const unsigned short* aptr = A  + ((size_t)(mt0*64  + arow)*1024 + acol);
    const unsigned short* bptr = Bw + ((size_t)(nt0*128 + brow)*1024 + bcol);

    uint4 a0 = ((const uint4*)aptr)[0], a1 = ((const uint4*)aptr)[1];
    uint4 b0 = ((const uint4*)bptr)[0], b1 = ((const uint4*)bptr)[1],
          b2 = ((const uint4*)bptr)[2], b3 = ((const uint4*)bptr)[3];

    f32x4 acc[4][2] = {};

    for (int kt = 0; kt < 16; ++kt) {
        const int cur = kt & 1;
        *((uint4*)&As[cur][arow][acol])    = a0;
        *((uint4*)&As[cur][arow][acol+8])  = a1;
        *((uint4*)&Bs[cur][brow][bcol])    = b0;
        *((uint4*)&Bs[cur][brow][bcol+8])  = b1;
        *((uint4*)&Bs[cur][brow][bcol+16]) = b2;
        *((uint4*)&Bs[cur][brow][bcol+24]) = b3;
        uint4 na0, na1, nb0, nb1, nb2, nb3;
        if (kt < 15) {
            const unsigned short* ap = aptr + (kt+1)*64;
            const unsigned short* bp = bptr + (kt+1)*64;
            na0 = ((const uint4*)ap)[0]; na1 = ((const uint4*)ap)[1];
            nb0 = ((const uint4*)bp)[0]; nb1 = ((const uint4*)bp)[1];
            nb2 = ((const uint4*)bp)[2]; nb3 = ((const uint4*)bp)[3];
        }
        __syncthreads();
        #pragma unroll
        for (int ks = 0; ks < 2; ++ks) {
            bf16x8 am[4], bn[2];
            #pragma unroll
            for (int i = 0; i < 4; ++i)
                am[i] = *(const bf16x8*)&As[cur][i*16 + ln][ks*32 + quad*8];
            #pragma unroll
            for (int i = 0; i < 2; ++i)
                bn[i] = *(const bf16x8*)&Bs[cur][wave*32 + i*16 + ln][ks*32 + quad*8];
            #pragma unroll
            for (int mi = 0; mi < 4; ++mi)
                #pragma unroll
                for (int ni = 0; ni < 2; ++ni)
                    acc[mi][ni] = __builtin_amdgcn_mfma_f32_16x16x32_bf16(
                        am[mi], bn[ni], acc[mi][ni], 0,0,0);
        }
        a0 = na0; a1 = na1;
        b0 = nb0; b1 = nb1; b2 = nb2; b3 = nb3;
    }

    #pragma unroll
    for (int mi = 0; mi < 4; ++mi)
        #pragma unroll
        for (int ni = 0; ni < 2; ++ni) {
            int row = mt0*64 + mi*16 + quad*4;
            int col = nt0*128 + wave*32 + ni*16 + ln;
            float bv = bias[col];
            #pragma unroll
            for (int r = 0; r < 4; ++r)
                out[(size_t)(row + r)*1024 + col] = acc[mi][ni][r] + bv;
        }
}

// ---------------------------------------------------------------------------
extern "C" void kernel_launch(void* const* d_in, const int* in_sizes, int n_in,
                              void* d_out, int out_size, void* d_ws, size_t ws_size,
                              hipStream_t stream)
{
    const float* Q   = (const float*)d_in[0];
    const float* K   = (const float*)d_in[1];
    const float* V   = (const float*)d_in[2];
    const float* Wo  = (const float*)d_in[3];
    const float* Wb  = (const float*)d_in[4];
    const int* maskp = (const int*)d_in[5];
    float* out = (float*)d_out;

    // workspace layout (ushort units)
    unsigned short* Kb   = (unsigned short*)d_ws;
    unsigned short* Vtb  = Kb  + (size_t)B_*S_*D_;
    unsigned short* Wob  = Vtb + (size_t)B_*S_*D_;
    unsigned short* ctxb = Wob + (size_t)D_*D_;
    float* Pv = (float*)(ctxb + (size_t)B_*S_*D_);   // [B*H*64][32] partials

    prep_kernel<<<6144, 256, 0, stream>>>(K, V, Wo, Kb, Vtb, Wob, Pv);
    attn_kernel<<<512/2, 256, 0, stream>>>(Q, Kb, Vtb, Pv, ctxb, maskp);
    proj_kernel<<<dim3(8, 64), 256, 0, stream>>>(ctxb, Wob, Wb, out);
}